// Round 5
// baseline (266.421 us; speedup 1.0000x reference)
//
#include <hip/hip_runtime.h>
#include <math.h>

// Problem constants
#define BB  2
#define SS  2048
#define DD  1024
#define HH  16
#define DKK 64

constexpr float kScale = 0.125f;  // 1/sqrt(64)
// p = exp(s*kScale - 16) = 2^(s*C1 - C2); exp(-16) cancels in O = sum(p*v)/sum(p)
constexpr float kC1 = 0.18033688011112042f;  // kScale * log2(e)
constexpr float kC2 = 23.0831206542234144f;  // 16 * log2(e)

typedef __bf16 bf16x8 __attribute__((ext_vector_type(8)));
typedef float f32x4 __attribute__((ext_vector_type(4)));

// Async global->LDS, 16 B per lane. LDS dest must be WAVE-UNIFORM base;
// HW scatters lane i to base + i*16.
__device__ __forceinline__ void async_copy16(const void* g, void* l) {
  __builtin_amdgcn_global_load_lds(
      (const __attribute__((address_space(1))) void*)g,
      (__attribute__((address_space(3))) void*)l, 16, 0, 0);
}

// ---------------------------------------------------------------------------
// fp32 -> bf16 elementwise convert (n must be multiple of 2048)
// ---------------------------------------------------------------------------
__global__ __launch_bounds__(256) void cvt_bf16_kernel(
    const float* __restrict__ in, __bf16* __restrict__ out) {
  const size_t i = ((size_t)blockIdx.x * 256 + threadIdx.x) * 8;
  const float4 v0 = *(const float4*)(in + i);
  const float4 v1 = *(const float4*)(in + i + 4);
  bf16x8 o;
  o[0] = (__bf16)v0.x; o[1] = (__bf16)v0.y; o[2] = (__bf16)v0.z; o[3] = (__bf16)v0.w;
  o[4] = (__bf16)v1.x; o[5] = (__bf16)v1.y; o[6] = (__bf16)v1.z; o[7] = (__bf16)v1.w;
  *(bf16x8*)(out + i) = o;
}

// ---------------------------------------------------------------------------
// RoPE table: tab[m][pi] = (cos, sin) of pos[m] * theta^(-2pi/64). 512 blocks.
// ---------------------------------------------------------------------------
__global__ __launch_bounds__(256) void rope_table_kernel(
    const int* __restrict__ pos, float2* __restrict__ tab) {
  const int idx = blockIdx.x * 256 + threadIdx.x;  // 131072 = 4096*32
  const int m = idx >> 5, pi = idx & 31;
  const float inv = exp2f(-0.4152410118609203f * (float)pi);
  float sn, cs;
  __sincosf((float)pos[m] * inv, &sn, &cs);
  tab[idx] = make_float2(cs, sn);
}

// ---------------------------------------------------------------------------
// Weight transpose + bf16 convert: T[n][k] = W[k][n]. grid (16,16,4)
// ---------------------------------------------------------------------------
__global__ __launch_bounds__(256) void transpose_w_kernel(
    const float* __restrict__ W0, const float* __restrict__ W1,
    const float* __restrict__ W2, const float* __restrict__ W3,
    __bf16* __restrict__ T0, __bf16* __restrict__ T1,
    __bf16* __restrict__ T2, __bf16* __restrict__ T3) {
  __shared__ __bf16 tile[64][65];
  const float* W;
  __bf16* T;
  switch (blockIdx.z) {
    case 0: W = W0; T = T0; break;
    case 1: W = W1; T = T1; break;
    case 2: W = W2; T = T2; break;
    default: W = W3; T = T3; break;
  }
  const int k0 = blockIdx.y * 64, n0 = blockIdx.x * 64;
  const int c = threadIdx.x & 63, rg = threadIdx.x >> 6;
#pragma unroll
  for (int i = 0; i < 16; i++) {
    const int r = rg + i * 4;
    tile[r][c] = (__bf16)W[(size_t)(k0 + r) * DD + n0 + c];
  }
  __syncthreads();
#pragma unroll
  for (int i = 0; i < 16; i++) {
    const int r = rg + i * 4;
    T[(size_t)(n0 + r) * DD + k0 + c] = tile[c][r];
  }
}

// ---------------------------------------------------------------------------
// V transpose per head: vt[bh][d][s] = v[bh][s][d]. grid (32 s-tiles, 32 bh)
// ---------------------------------------------------------------------------
__global__ __launch_bounds__(256) void vtrans_kernel(
    const __bf16* __restrict__ v, __bf16* __restrict__ vt) {
  __shared__ __bf16 tile[64][72];
  const int st = blockIdx.x, bh = blockIdx.y;
  const __bf16* vb = v + (size_t)bh * SS * DKK + (size_t)st * 64 * DKK;
  __bf16* vo = vt + (size_t)bh * DKK * SS + st * 64;
  const int t = threadIdx.x;
  {
    const int r = t >> 2, c0 = (t & 3) * 16;
    bf16x8 a = *(const bf16x8*)(vb + r * DKK + c0);
    bf16x8 b = *(const bf16x8*)(vb + r * DKK + c0 + 8);
#pragma unroll
    for (int i = 0; i < 8; i++) tile[r][c0 + i] = a[i];
#pragma unroll
    for (int i = 0; i < 8; i++) tile[r][c0 + 8 + i] = b[i];
  }
  __syncthreads();
  {
    const int d = t >> 2, s0 = (t & 3) * 16;
    bf16x8 a, b;
#pragma unroll
    for (int i = 0; i < 8; i++) a[i] = tile[s0 + i][d];
#pragma unroll
    for (int i = 0; i < 8; i++) b[i] = tile[s0 + 8 + i][d];
    *(bf16x8*)(vo + (size_t)d * SS + s0) = a;
    *(bf16x8*)(vo + (size_t)d * SS + s0 + 8) = b;
  }
}

// ---------------------------------------------------------------------------
// m97-style GEMM core with XOR chunk-swizzled LDS (conflict-free B-frag reads)
// C[128,128] += A[128,K] @ Bt[128,K]^T  (K = DD = 1024)
// ---------------------------------------------------------------------------
__device__ __forceinline__ void gemm_core(
    const __bf16* __restrict__ A, const __bf16* __restrict__ Bt,
    int bm, int bn, f32x4 (&acc)[4][4], __bf16* As, __bf16* Bs) {
  const int t = threadIdx.x;
  const int lane = t & 63, wave = t >> 6;
  const int col = lane & 15, quad = lane >> 4;
  const int wm = (wave & 1) * 64, wn = (wave >> 1) * 64;
  const int r8 = lane >> 3;             // row within 8-row slab
  const int cg = (lane & 7) ^ r8;       // swizzled global chunk
  const __bf16* ag = A + (size_t)(bm + wave * 32 + r8) * DD + cg * 8;
  const __bf16* bg = Bt + (size_t)(bn + wave * 32 + r8) * DD + cg * 8;
  __bf16* asb = As + wave * 32 * 64;
  __bf16* bsb = Bs + wave * 32 * 64;

  for (int kt = 0; kt < DD; kt += 64) {
#pragma unroll
    for (int c = 0; c < 4; c++) {
      async_copy16(ag + (size_t)c * 8 * DD + kt, asb + c * 512);
      async_copy16(bg + (size_t)c * 8 * DD + kt, bsb + c * 512);
    }
    __syncthreads();
#pragma unroll
    for (int ks = 0; ks < 2; ks++) {
      bf16x8 af[4], bf[4];
#pragma unroll
      for (int i = 0; i < 4; i++)
        af[i] = *(const bf16x8*)(As + (wm + i * 16 + col) * 64 +
                                 (((ks * 4 + quad) ^ (col & 7)) * 8));
#pragma unroll
      for (int j = 0; j < 4; j++)
        bf[j] = *(const bf16x8*)(Bs + (wn + j * 16 + col) * 64 +
                                 (((ks * 4 + quad) ^ (col & 7)) * 8));
#pragma unroll
      for (int i = 0; i < 4; i++)
#pragma unroll
        for (int j = 0; j < 4; j++)
          acc[i][j] =
              __builtin_amdgcn_mfma_f32_16x16x32_bf16(af[i], bf[j], acc[i][j], 0, 0, 0);
    }
    __syncthreads();
  }
}

// ---------------------------------------------------------------------------
// Fused Q/K/V projection. grid (24, 32): blockIdx.x = mat*8 + n-tile.
// RoPE via precomputed table (cos,sin).
// ---------------------------------------------------------------------------
__global__ __launch_bounds__(256) void qkv_gemm_kernel(
    const __bf16* __restrict__ xb, const __bf16* __restrict__ WqT,
    const __bf16* __restrict__ WkT, const __bf16* __restrict__ WvT,
    const float* __restrict__ bq, const float* __restrict__ bk,
    const float* __restrict__ bv, const float2* __restrict__ ropetab,
    __bf16* __restrict__ qo, __bf16* __restrict__ ko, __bf16* __restrict__ vo) {
  __shared__ __bf16 As[128 * 64];
  __shared__ __bf16 Bs[128 * 64];
  const int mat = blockIdx.x >> 3;
  const int bn = (blockIdx.x & 7) * 128;
  const int bm = blockIdx.y * 128;
  const __bf16* Bt = mat == 0 ? WqT : (mat == 1 ? WkT : WvT);
  const float* bias = mat == 0 ? bq : (mat == 1 ? bk : bv);
  __bf16* out = mat == 0 ? qo : (mat == 1 ? ko : vo);

  f32x4 acc[4][4] = {};
  gemm_core(xb, Bt, bm, bn, acc, As, Bs);

  const int t = threadIdx.x, lane = t & 63, wave = t >> 6;
  const int col = lane & 15, quad = lane >> 4;
  const int wm = (wave & 1) * 64, wn = (wave >> 1) * 64;
  const bool rope = (mat < 2);
#pragma unroll
  for (int i = 0; i < 4; i++) {
#pragma unroll
    for (int j = 0; j < 4; j++) {
      const int n = bn + wn + j * 16 + col;
      const float bb = bias[n];
      const int pi = (n & 63) >> 1;
#pragma unroll
      for (int r = 0; r < 4; r++) {
        const int m = bm + wm + i * 16 + quad * 4 + r;
        float v = acc[i][j][r] + bb;
        if (rope) {
          const float other = __shfl_xor(v, 1, 64);
          const float2 cssn = ropetab[(size_t)m * 32 + pi];
          v = (n & 1) ? (other * cssn.y + v * cssn.x)
                      : (v * cssn.x - other * cssn.y);
        }
        const int h = n >> 6, dk = n & 63;
        const int b = m >> 11, s = m & (SS - 1);
        out[((size_t)(b * HH + h) * SS + s) * DKK + dk] = (__bf16)v;
      }
    }
  }
}

// ---------------------------------------------------------------------------
// O projection: out[M,N] fp32 = ob[M,K] @ WoT[N,K]^T + bo. grid (8, 32).
// ---------------------------------------------------------------------------
__global__ __launch_bounds__(256) void oproj_gemm_kernel(
    const __bf16* __restrict__ ob, const __bf16* __restrict__ WoT,
    const float* __restrict__ bo, float* __restrict__ out) {
  __shared__ __bf16 As[128 * 64];
  __shared__ __bf16 Bs[128 * 64];
  const int bn = blockIdx.x * 128;
  const int bm = blockIdx.y * 128;
  f32x4 acc[4][4] = {};
  gemm_core(ob, WoT, bm, bn, acc, As, Bs);

  const int t = threadIdx.x, lane = t & 63, wave = t >> 6;
  const int col = lane & 15, quad = lane >> 4;
  const int wm = (wave & 1) * 64, wn = (wave >> 1) * 64;
#pragma unroll
  for (int i = 0; i < 4; i++) {
#pragma unroll
    for (int j = 0; j < 4; j++) {
      const int n = bn + wn + j * 16 + col;
      const float bb = bo[n];
#pragma unroll
      for (int r = 0; r < 4; r++) {
        const int m = bm + wm + i * 16 + quad * 4 + r;
        out[(size_t)m * DD + n] = acc[i][j][r] + bb;
      }
    }
  }
}

// ---------------------------------------------------------------------------
// MFMA flash attention, fixed-max softmax, double-buffered K/V, 1 barrier/iter.
// grid (32, 32): x -> qt = 31-x (heavy blocks dispatch first), y -> bh.
// Block = 64 Q-rows, 4 waves x 16 rows. K-tile = 64 tokens.
// p = exp(s/8 - 16); the exp(-16) factor cancels in O = sum(p v)/sum(p).
// l kept as per-lane partials, reduced once at the end (no per-iter shuffles).
// q,k in [B,H,S,DK]; vt in [B,H,DK,S]; o out [B,S,H,DK] bf16.
// ---------------------------------------------------------------------------
__global__ __launch_bounds__(256) void flash_attn_mfma_kernel(
    const __bf16* __restrict__ q, const __bf16* __restrict__ k,
    const __bf16* __restrict__ vt, __bf16* __restrict__ o) {
  __shared__ __bf16 Ks[2][64 * 64];    // [j][dk], chunk-swizzled
  __shared__ __bf16 Vs[2][64 * 64];    // [d][j],  chunk-swizzled
  __shared__ __bf16 Ps[4][16 * 72];    // per-wave [row][j], stride 72

  const int qt = 31 - blockIdx.x;      // heavy-first dispatch
  const int bh = blockIdx.y;
  const int t = threadIdx.x, lane = t & 63, wave = t >> 6;
  const int col = lane & 15, quad = lane >> 4;
  const int r8 = lane >> 3;            // row in 8-row slab
  const int cg = (lane & 7) ^ r8;      // swizzled global chunk

  const __bf16* qb = q + (size_t)bh * SS * DKK;
  const __bf16* kb = k + (size_t)bh * SS * DKK;
  const __bf16* vtb = vt + (size_t)bh * DKK * SS;
  const int b = bh / HH, h = bh % HH;
  __bf16* pw = (__bf16*)Ps[wave];
  const int rbase = qt * 64 + wave * 16;

  // Q fragments (held in registers all kernel)
  bf16x8 qf[2];
#pragma unroll
  for (int ks = 0; ks < 2; ks++)
    qf[ks] = *(const bf16x8*)(qb + (size_t)(rbase + col) * DKK + ks * 32 +
                              quad * 8);

  f32x4 oacc[4] = {};
  float l_lane[4] = {0.f, 0.f, 0.f, 0.f};

  // Prologue: stage tile 0 into buffer 0
#pragma unroll
  for (int i = 0; i < 2; i++) {
    const int slab = wave * 2 + i;
    async_copy16(kb + (size_t)(slab * 8 + r8) * DKK + cg * 8,
                 Ks[0] + slab * 512);
    async_copy16(vtb + (size_t)(slab * 8 + r8) * SS + cg * 8,
                 Vs[0] + slab * 512);
  }

  for (int kt = 0; kt <= qt; kt++) {
    const int cur = kt & 1;
    __syncthreads();  // drains this iter's staged loads (vmcnt(0) + barrier)

    // Prefetch next tile into the other buffer; its drain happens at the
    // NEXT barrier, after this iteration's full compute has overlapped it.
    if (kt < qt) {
#pragma unroll
      for (int i = 0; i < 2; i++) {
        const int slab = wave * 2 + i;
        async_copy16(kb + (size_t)((kt + 1) * 64 + slab * 8 + r8) * DKK + cg * 8,
                     Ks[cur ^ 1] + slab * 512);
        async_copy16(vtb + (size_t)(slab * 8 + r8) * SS + (kt + 1) * 64 + cg * 8,
                     Vs[cur ^ 1] + slab * 512);
      }
    }

    // ---- QK^T: sc[ct], D-row = quad*4+r, D-col(token) = ct*16+col ----
    f32x4 sc[4] = {};
#pragma unroll
    for (int ct = 0; ct < 4; ct++)
#pragma unroll
      for (int ks = 0; ks < 2; ks++) {
        const bf16x8 kf =
            *(const bf16x8*)(Ks[cur] + (ct * 16 + col) * 64 +
                             (((ks * 4 + quad) ^ (col & 7)) * 8));
        sc[ct] = __builtin_amdgcn_mfma_f32_16x16x32_bf16(qf[ks], kf, sc[ct],
                                                         0, 0, 0);
      }

    // ---- fixed-max softmax: p = 2^(s*C1 - C2); store P, accumulate l ----
    const bool diag = (kt == qt);
#pragma unroll
    for (int ct = 0; ct < 4; ct++)
#pragma unroll
      for (int r = 0; r < 4; r++) {
        float p = exp2f(sc[ct][r] * kC1 - kC2);
        if (diag && (kt * 64 + ct * 16 + col) > (rbase + quad * 4 + r))
          p = 0.0f;
        l_lane[r] += p;
        pw[(quad * 4 + r) * 72 + ct * 16 + col] = (__bf16)p;
      }

    // ---- PV: O[16 rows][dt*16+col] += P @ Vt^T (wave-private P) ----
    {
      bf16x8 pf[2];
#pragma unroll
      for (int ks = 0; ks < 2; ks++)
        pf[ks] = *(const bf16x8*)(pw + col * 72 + ks * 32 + quad * 8);
#pragma unroll
      for (int dt = 0; dt < 4; dt++)
#pragma unroll
        for (int ks = 0; ks < 2; ks++) {
          const bf16x8 vf =
              *(const bf16x8*)(Vs[cur] + (dt * 16 + col) * 64 +
                               (((ks * 4 + quad) ^ (col & 7)) * 8));
          oacc[dt] = __builtin_amdgcn_mfma_f32_16x16x32_bf16(pf[ks], vf,
                                                             oacc[dt], 0, 0, 0);
        }
    }
  }

  // Epilogue: reduce l over the 16 col-lanes, normalize, write o [B,S,H,DK]
#pragma unroll
  for (int r = 0; r < 4; r++) {
    float l = l_lane[r];
#pragma unroll
    for (int w = 1; w < 16; w <<= 1) l += __shfl_xor(l, w, 64);
    const float inv_l = 1.0f / l;
    const int s = rbase + quad * 4 + r;
#pragma unroll
    for (int dt = 0; dt < 4; dt++)
      o[((size_t)(b * SS + s) * HH + h) * DKK + dt * 16 + col] =
          (__bf16)(oacc[dt][r] * inv_l);
  }
}

// ---------------------------------------------------------------------------
extern "C" void kernel_launch(void* const* d_in, const int* in_sizes, int n_in,
                              void* d_out, int out_size, void* d_ws,
                              size_t ws_size, hipStream_t stream) {
  const float* x  = (const float*)d_in[0];
  const int*  pos = (const int*)d_in[1];
  const float* Wq = (const float*)d_in[2];
  const float* bq = (const float*)d_in[3];
  const float* Wk = (const float*)d_in[4];
  const float* bk = (const float*)d_in[5];
  const float* Wv = (const float*)d_in[6];
  const float* bv = (const float*)d_in[7];
  const float* Wo = (const float*)d_in[8];
  const float* bo = (const float*)d_in[9];
  float* out = (float*)d_out;

  char* ws = (char*)d_ws;
  __bf16* xb  = (__bf16*)(ws);                          // 8 MB
  __bf16* WqT = (__bf16*)(ws + ((size_t)8  << 20));     // 2 MB each
  __bf16* WkT = (__bf16*)(ws + ((size_t)10 << 20));
  __bf16* WvT = (__bf16*)(ws + ((size_t)12 << 20));
  __bf16* WoT = (__bf16*)(ws + ((size_t)14 << 20));
  __bf16* qb  = (__bf16*)(ws + ((size_t)16 << 20));     // 8 MB each
  __bf16* kb  = (__bf16*)(ws + ((size_t)24 << 20));
  __bf16* vb  = (__bf16*)(ws + ((size_t)32 << 20));
  __bf16* vtb = (__bf16*)(ws + ((size_t)40 << 20));
  __bf16* ob  = (__bf16*)(ws + ((size_t)48 << 20));
  float2* rtab = (float2*)(ws + ((size_t)56 << 20));    // 1 MB; total 57 MB

  cvt_bf16_kernel<<<2048, 256, 0, stream>>>(x, xb);
  rope_table_kernel<<<512, 256, 0, stream>>>(pos, rtab);
  transpose_w_kernel<<<dim3(16, 16, 4), 256, 0, stream>>>(Wq, Wk, Wv, Wo, WqT,
                                                          WkT, WvT, WoT);
  qkv_gemm_kernel<<<dim3(24, 32), 256, 0, stream>>>(xb, WqT, WkT, WvT, bq, bk,
                                                    bv, rtab, qb, kb, vb);
  vtrans_kernel<<<dim3(32, 32), 256, 0, stream>>>(vb, vtb);
  flash_attn_mfma_kernel<<<dim3(32, 32), 256, 0, stream>>>(qb, kb, vtb, ob);
  oproj_gemm_kernel<<<dim3(8, 32), 256, 0, stream>>>(ob, WoT, bo, out);
}

// Round 6
// 234.353 us; speedup vs baseline: 1.1368x; 1.1368x over previous
//
#include <hip/hip_runtime.h>
#include <math.h>

// Problem constants
#define BB  2
#define SS  2048
#define DD  1024
#define HH  16
#define DKK 64

constexpr float kScale = 0.125f;  // 1/sqrt(64)
// p = exp(s*kScale - 16) = 2^(s*C1 - C2); exp(-16) cancels in O = sum(p*v)/sum(p)
constexpr float kC1 = 0.18033688011112042f;  // kScale * log2(e)
constexpr float kC2 = 23.0831206542234144f;  // 16 * log2(e)

typedef __bf16 bf16x8 __attribute__((ext_vector_type(8)));
typedef float f32x4 __attribute__((ext_vector_type(4)));

// Async global->LDS, 16 B per lane. LDS dest must be WAVE-UNIFORM base;
// HW scatters lane i to base + i*16.
__device__ __forceinline__ void async_copy16(const void* g, void* l) {
  __builtin_amdgcn_global_load_lds(
      (const __attribute__((address_space(1))) void*)g,
      (__attribute__((address_space(3))) void*)l, 16, 0, 0);
}

// ---------------------------------------------------------------------------
// fp32 -> bf16 elementwise convert (n must be multiple of 2048)
// ---------------------------------------------------------------------------
__global__ __launch_bounds__(256) void cvt_bf16_kernel(
    const float* __restrict__ in, __bf16* __restrict__ out) {
  const size_t i = ((size_t)blockIdx.x * 256 + threadIdx.x) * 8;
  const float4 v0 = *(const float4*)(in + i);
  const float4 v1 = *(const float4*)(in + i + 4);
  bf16x8 o;
  o[0] = (__bf16)v0.x; o[1] = (__bf16)v0.y; o[2] = (__bf16)v0.z; o[3] = (__bf16)v0.w;
  o[4] = (__bf16)v1.x; o[5] = (__bf16)v1.y; o[6] = (__bf16)v1.z; o[7] = (__bf16)v1.w;
  *(bf16x8*)(out + i) = o;
}

// ---------------------------------------------------------------------------
// RoPE table: tab[m][pi] = (cos, sin) of pos[m] * theta^(-2pi/64). 512 blocks.
// ---------------------------------------------------------------------------
__global__ __launch_bounds__(256) void rope_table_kernel(
    const int* __restrict__ pos, float2* __restrict__ tab) {
  const int idx = blockIdx.x * 256 + threadIdx.x;  // 131072 = 4096*32
  const int m = idx >> 5, pi = idx & 31;
  const float inv = exp2f(-0.4152410118609203f * (float)pi);
  float sn, cs;
  __sincosf((float)pos[m] * inv, &sn, &cs);
  tab[idx] = make_float2(cs, sn);
}

// ---------------------------------------------------------------------------
// Weight transpose + bf16 convert: T[n][k] = W[k][n]. grid (16,16,4)
// ---------------------------------------------------------------------------
__global__ __launch_bounds__(256) void transpose_w_kernel(
    const float* __restrict__ W0, const float* __restrict__ W1,
    const float* __restrict__ W2, const float* __restrict__ W3,
    __bf16* __restrict__ T0, __bf16* __restrict__ T1,
    __bf16* __restrict__ T2, __bf16* __restrict__ T3) {
  __shared__ __bf16 tile[64][65];
  const float* W;
  __bf16* T;
  switch (blockIdx.z) {
    case 0: W = W0; T = T0; break;
    case 1: W = W1; T = T1; break;
    case 2: W = W2; T = T2; break;
    default: W = W3; T = T3; break;
  }
  const int k0 = blockIdx.y * 64, n0 = blockIdx.x * 64;
  const int c = threadIdx.x & 63, rg = threadIdx.x >> 6;
#pragma unroll
  for (int i = 0; i < 16; i++) {
    const int r = rg + i * 4;
    tile[r][c] = (__bf16)W[(size_t)(k0 + r) * DD + n0 + c];
  }
  __syncthreads();
#pragma unroll
  for (int i = 0; i < 16; i++) {
    const int r = rg + i * 4;
    T[(size_t)(n0 + r) * DD + k0 + c] = tile[c][r];
  }
}

// ---------------------------------------------------------------------------
// V transpose per head: vt[bh][d][s] = v[bh][s][d]. grid (32 s-tiles, 32 bh)
// ---------------------------------------------------------------------------
__global__ __launch_bounds__(256) void vtrans_kernel(
    const __bf16* __restrict__ v, __bf16* __restrict__ vt) {
  __shared__ __bf16 tile[64][72];
  const int st = blockIdx.x, bh = blockIdx.y;
  const __bf16* vb = v + (size_t)bh * SS * DKK + (size_t)st * 64 * DKK;
  __bf16* vo = vt + (size_t)bh * DKK * SS + st * 64;
  const int t = threadIdx.x;
  {
    const int r = t >> 2, c0 = (t & 3) * 16;
    bf16x8 a = *(const bf16x8*)(vb + r * DKK + c0);
    bf16x8 b = *(const bf16x8*)(vb + r * DKK + c0 + 8);
#pragma unroll
    for (int i = 0; i < 8; i++) tile[r][c0 + i] = a[i];
#pragma unroll
    for (int i = 0; i < 8; i++) tile[r][c0 + 8 + i] = b[i];
  }
  __syncthreads();
  {
    const int d = t >> 2, s0 = (t & 3) * 16;
    bf16x8 a, b;
#pragma unroll
    for (int i = 0; i < 8; i++) a[i] = tile[s0 + i][d];
#pragma unroll
    for (int i = 0; i < 8; i++) b[i] = tile[s0 + 8 + i][d];
    *(bf16x8*)(vo + (size_t)d * SS + s0) = a;
    *(bf16x8*)(vo + (size_t)d * SS + s0 + 8) = b;
  }
}

// ---------------------------------------------------------------------------
// m97-style GEMM core with XOR chunk-swizzled LDS (conflict-free B-frag reads)
// C[128,128] += A[128,K] @ Bt[128,K]^T  (K = DD = 1024)
// ---------------------------------------------------------------------------
__device__ __forceinline__ void gemm_core(
    const __bf16* __restrict__ A, const __bf16* __restrict__ Bt,
    int bm, int bn, f32x4 (&acc)[4][4], __bf16* As, __bf16* Bs) {
  const int t = threadIdx.x;
  const int lane = t & 63, wave = t >> 6;
  const int col = lane & 15, quad = lane >> 4;
  const int wm = (wave & 1) * 64, wn = (wave >> 1) * 64;
  const int r8 = lane >> 3;             // row within 8-row slab
  const int cg = (lane & 7) ^ r8;       // swizzled global chunk
  const __bf16* ag = A + (size_t)(bm + wave * 32 + r8) * DD + cg * 8;
  const __bf16* bg = Bt + (size_t)(bn + wave * 32 + r8) * DD + cg * 8;
  __bf16* asb = As + wave * 32 * 64;
  __bf16* bsb = Bs + wave * 32 * 64;

  for (int kt = 0; kt < DD; kt += 64) {
#pragma unroll
    for (int c = 0; c < 4; c++) {
      async_copy16(ag + (size_t)c * 8 * DD + kt, asb + c * 512);
      async_copy16(bg + (size_t)c * 8 * DD + kt, bsb + c * 512);
    }
    __syncthreads();
#pragma unroll
    for (int ks = 0; ks < 2; ks++) {
      bf16x8 af[4], bf[4];
#pragma unroll
      for (int i = 0; i < 4; i++)
        af[i] = *(const bf16x8*)(As + (wm + i * 16 + col) * 64 +
                                 (((ks * 4 + quad) ^ (col & 7)) * 8));
#pragma unroll
      for (int j = 0; j < 4; j++)
        bf[j] = *(const bf16x8*)(Bs + (wn + j * 16 + col) * 64 +
                                 (((ks * 4 + quad) ^ (col & 7)) * 8));
#pragma unroll
      for (int i = 0; i < 4; i++)
#pragma unroll
        for (int j = 0; j < 4; j++)
          acc[i][j] =
              __builtin_amdgcn_mfma_f32_16x16x32_bf16(af[i], bf[j], acc[i][j], 0, 0, 0);
    }
    __syncthreads();
  }
}

// ---------------------------------------------------------------------------
// Fused Q/K/V projection. grid (24, 32): blockIdx.x = mat*8 + n-tile.
// RoPE via precomputed table (cos,sin).
// ---------------------------------------------------------------------------
__global__ __launch_bounds__(256) void qkv_gemm_kernel(
    const __bf16* __restrict__ xb, const __bf16* __restrict__ WqT,
    const __bf16* __restrict__ WkT, const __bf16* __restrict__ WvT,
    const float* __restrict__ bq, const float* __restrict__ bk,
    const float* __restrict__ bv, const float2* __restrict__ ropetab,
    __bf16* __restrict__ qo, __bf16* __restrict__ ko, __bf16* __restrict__ vo) {
  __shared__ __bf16 As[128 * 64];
  __shared__ __bf16 Bs[128 * 64];
  const int mat = blockIdx.x >> 3;
  const int bn = (blockIdx.x & 7) * 128;
  const int bm = blockIdx.y * 128;
  const __bf16* Bt = mat == 0 ? WqT : (mat == 1 ? WkT : WvT);
  const float* bias = mat == 0 ? bq : (mat == 1 ? bk : bv);
  __bf16* out = mat == 0 ? qo : (mat == 1 ? ko : vo);

  f32x4 acc[4][4] = {};
  gemm_core(xb, Bt, bm, bn, acc, As, Bs);

  const int t = threadIdx.x, lane = t & 63, wave = t >> 6;
  const int col = lane & 15, quad = lane >> 4;
  const int wm = (wave & 1) * 64, wn = (wave >> 1) * 64;
  const bool rope = (mat < 2);
#pragma unroll
  for (int i = 0; i < 4; i++) {
#pragma unroll
    for (int j = 0; j < 4; j++) {
      const int n = bn + wn + j * 16 + col;
      const float bb = bias[n];
      const int pi = (n & 63) >> 1;
#pragma unroll
      for (int r = 0; r < 4; r++) {
        const int m = bm + wm + i * 16 + quad * 4 + r;
        float v = acc[i][j][r] + bb;
        if (rope) {
          const float other = __shfl_xor(v, 1, 64);
          const float2 cssn = ropetab[(size_t)m * 32 + pi];
          v = (n & 1) ? (other * cssn.y + v * cssn.x)
                      : (v * cssn.x - other * cssn.y);
        }
        const int h = n >> 6, dk = n & 63;
        const int b = m >> 11, s = m & (SS - 1);
        out[((size_t)(b * HH + h) * SS + s) * DKK + dk] = (__bf16)v;
      }
    }
  }
}

// ---------------------------------------------------------------------------
// O projection: out[M,N] fp32 = ob[M,K] @ WoT[N,K]^T + bo. grid (8, 32).
// ---------------------------------------------------------------------------
__global__ __launch_bounds__(256) void oproj_gemm_kernel(
    const __bf16* __restrict__ ob, const __bf16* __restrict__ WoT,
    const float* __restrict__ bo, float* __restrict__ out) {
  __shared__ __bf16 As[128 * 64];
  __shared__ __bf16 Bs[128 * 64];
  const int bn = blockIdx.x * 128;
  const int bm = blockIdx.y * 128;
  f32x4 acc[4][4] = {};
  gemm_core(ob, WoT, bm, bn, acc, As, Bs);

  const int t = threadIdx.x, lane = t & 63, wave = t >> 6;
  const int col = lane & 15, quad = lane >> 4;
  const int wm = (wave & 1) * 64, wn = (wave >> 1) * 64;
#pragma unroll
  for (int i = 0; i < 4; i++) {
#pragma unroll
    for (int j = 0; j < 4; j++) {
      const int n = bn + wn + j * 16 + col;
      const float bb = bo[n];
#pragma unroll
      for (int r = 0; r < 4; r++) {
        const int m = bm + wm + i * 16 + quad * 4 + r;
        out[(size_t)m * DD + n] = acc[i][j][r] + bb;
      }
    }
  }
}

// ---------------------------------------------------------------------------
// MFMA flash attention: R4 shell (paired load-balanced grid, single-buffered
// K/V) + fixed-max softmax (no per-iter cross-lane reductions).
// Block = (bh, pair p): Q-tile p then 31-p -> 33 iters per block, constant.
// 4 waves x 16 Q-rows. K-tile = 64 tokens.
// p = exp(s/8 - 16) = 2^(s*C1 - C2); exp(-16) cancels in O = sum(p v)/sum(p).
// l kept as per-lane partials, reduced once per phase end.
// q,k in [B,H,S,DK]; vt in [B,H,DK,S]; o out [B,S,H,DK] bf16.
// ---------------------------------------------------------------------------
__global__ __launch_bounds__(256) void flash_attn_mfma_kernel(
    const __bf16* __restrict__ q, const __bf16* __restrict__ k,
    const __bf16* __restrict__ vt, __bf16* __restrict__ o) {
  __shared__ __bf16 Ks[64 * 64];       // [j][dk], chunk-swizzled
  __shared__ __bf16 Vs[64 * 64];       // [d][j],  chunk-swizzled
  __shared__ __bf16 Ps[4][16 * 72];    // per-wave [row][j], stride 72

  const int bh = blockIdx.x;   // 0..31
  const int pr = blockIdx.y;   // 0..15
  const int t = threadIdx.x, lane = t & 63, wave = t >> 6;
  const int col = lane & 15, quad = lane >> 4;
  const int r8 = lane >> 3;            // row in 8-row slab
  const int cg = (lane & 7) ^ r8;      // swizzled global chunk

  const __bf16* qb = q + (size_t)bh * SS * DKK;
  const __bf16* kb = k + (size_t)bh * SS * DKK;
  const __bf16* vtb = vt + (size_t)bh * DKK * SS;
  const int b = bh / HH, h = bh % HH;
  __bf16* pw = (__bf16*)Ps[wave];

#pragma unroll
  for (int phase = 0; phase < 2; phase++) {
    const int qt = phase == 0 ? pr : (31 - pr);
    const int rbase = qt * 64 + wave * 16;

    // Q fragments for this phase (held in registers)
    bf16x8 qf[2];
#pragma unroll
    for (int ks = 0; ks < 2; ks++)
      qf[ks] = *(const bf16x8*)(qb + (size_t)(rbase + col) * DKK + ks * 32 +
                                quad * 8);

    f32x4 oacc[4] = {};
    float l_lane[4] = {0.f, 0.f, 0.f, 0.f};

    for (int kt = 0; kt <= qt; kt++) {
      // Stage K tile [64][64] and Vt tile [64][64]; wave w covers slabs
      // w*2 and w*2+1 (8 rows each).
#pragma unroll
      for (int i = 0; i < 2; i++) {
        const int slab = wave * 2 + i;
        async_copy16(kb + (size_t)(kt * 64 + slab * 8 + r8) * DKK + cg * 8,
                     Ks + slab * 512);
        async_copy16(vtb + (size_t)(slab * 8 + r8) * SS + kt * 64 + cg * 8,
                     Vs + slab * 512);
      }
      __syncthreads();

      // ---- QK^T: sc[ct], D-row = quad*4+r, D-col(token) = ct*16+col ----
      f32x4 sc[4] = {};
#pragma unroll
      for (int ct = 0; ct < 4; ct++)
#pragma unroll
        for (int ks = 0; ks < 2; ks++) {
          const bf16x8 kf = *(const bf16x8*)(Ks + (ct * 16 + col) * 64 +
                                             (((ks * 4 + quad) ^ (col & 7)) * 8));
          sc[ct] = __builtin_amdgcn_mfma_f32_16x16x32_bf16(qf[ks], kf, sc[ct],
                                                           0, 0, 0);
        }

      // ---- fixed-max softmax: p = 2^(s*C1 - C2); store P, accumulate l ----
      const bool diag = (kt == qt);
#pragma unroll
      for (int ct = 0; ct < 4; ct++)
#pragma unroll
        for (int r = 0; r < 4; r++) {
          float p = exp2f(sc[ct][r] * kC1 - kC2);
          if (diag && (kt * 64 + ct * 16 + col) > (rbase + quad * 4 + r))
            p = 0.0f;
          l_lane[r] += p;
          pw[(quad * 4 + r) * 72 + ct * 16 + col] = (__bf16)p;
        }

      // ---- PV: O[16 rows][dt*16+col] += P @ Vt^T (wave-private P) ----
      {
        bf16x8 pf[2];
#pragma unroll
        for (int ks = 0; ks < 2; ks++)
          pf[ks] = *(const bf16x8*)(pw + col * 72 + ks * 32 + quad * 8);
#pragma unroll
        for (int dt = 0; dt < 4; dt++)
#pragma unroll
          for (int ks = 0; ks < 2; ks++) {
            const bf16x8 vf = *(const bf16x8*)(Vs + (dt * 16 + col) * 64 +
                                               (((ks * 4 + quad) ^ (col & 7)) * 8));
            oacc[dt] = __builtin_amdgcn_mfma_f32_16x16x32_bf16(pf[ks], vf,
                                                               oacc[dt], 0, 0, 0);
          }
      }
      __syncthreads();
    }

    // Phase epilogue: reduce l over 16 token-lanes, normalize, write o
#pragma unroll
    for (int r = 0; r < 4; r++) {
      float l = l_lane[r];
#pragma unroll
      for (int w = 1; w < 16; w <<= 1) l += __shfl_xor(l, w, 64);
      const float inv_l = 1.0f / l;
      const int s = rbase + quad * 4 + r;
#pragma unroll
      for (int dt = 0; dt < 4; dt++)
        o[((size_t)(b * SS + s) * HH + h) * DKK + dt * 16 + col] =
            (__bf16)(oacc[dt][r] * inv_l);
    }
  }
}

// ---------------------------------------------------------------------------
extern "C" void kernel_launch(void* const* d_in, const int* in_sizes, int n_in,
                              void* d_out, int out_size, void* d_ws,
                              size_t ws_size, hipStream_t stream) {
  const float* x  = (const float*)d_in[0];
  const int*  pos = (const int*)d_in[1];
  const float* Wq = (const float*)d_in[2];
  const float* bq = (const float*)d_in[3];
  const float* Wk = (const float*)d_in[4];
  const float* bk = (const float*)d_in[5];
  const float* Wv = (const float*)d_in[6];
  const float* bv = (const float*)d_in[7];
  const float* Wo = (const float*)d_in[8];
  const float* bo = (const float*)d_in[9];
  float* out = (float*)d_out;

  char* ws = (char*)d_ws;
  __bf16* xb  = (__bf16*)(ws);                          // 8 MB
  __bf16* WqT = (__bf16*)(ws + ((size_t)8  << 20));     // 2 MB each
  __bf16* WkT = (__bf16*)(ws + ((size_t)10 << 20));
  __bf16* WvT = (__bf16*)(ws + ((size_t)12 << 20));
  __bf16* WoT = (__bf16*)(ws + ((size_t)14 << 20));
  __bf16* qb  = (__bf16*)(ws + ((size_t)16 << 20));     // 8 MB each
  __bf16* kb  = (__bf16*)(ws + ((size_t)24 << 20));
  __bf16* vb  = (__bf16*)(ws + ((size_t)32 << 20));
  __bf16* vtb = (__bf16*)(ws + ((size_t)40 << 20));
  __bf16* ob  = (__bf16*)(ws + ((size_t)48 << 20));
  float2* rtab = (float2*)(ws + ((size_t)56 << 20));    // 1 MB; total 57 MB

  cvt_bf16_kernel<<<2048, 256, 0, stream>>>(x, xb);
  rope_table_kernel<<<512, 256, 0, stream>>>(pos, rtab);
  transpose_w_kernel<<<dim3(16, 16, 4), 256, 0, stream>>>(Wq, Wk, Wv, Wo, WqT,
                                                          WkT, WvT, WoT);
  qkv_gemm_kernel<<<dim3(24, 32), 256, 0, stream>>>(xb, WqT, WkT, WvT, bq, bk,
                                                    bv, rtab, qb, kb, vb);
  vtrans_kernel<<<dim3(32, 32), 256, 0, stream>>>(vb, vtb);
  flash_attn_mfma_kernel<<<dim3(32, 16), 256, 0, stream>>>(qb, kb, vtb, ob);
  oproj_gemm_kernel<<<dim3(8, 32), 256, 0, stream>>>(ob, WoT, bo, out);
}

// Round 8
// 206.034 us; speedup vs baseline: 1.2931x; 1.1374x over previous
//
#include <hip/hip_runtime.h>
#include <math.h>

// Problem constants
#define BB  2
#define SS  2048
#define DD  1024
#define HH  16
#define DKK 64

constexpr float kScale = 0.125f;  // 1/sqrt(64)
// p = exp(s*kScale - 16) = 2^(s*C1 - C2); exp(-16) cancels in O = sum(p*v)/sum(p)
constexpr float kC1 = 0.18033688011112042f;  // kScale * log2(e)
constexpr float kC2 = 23.0831206542234144f;  // 16 * log2(e)

typedef __bf16 bf16x8 __attribute__((ext_vector_type(8)));
typedef float f32x4 __attribute__((ext_vector_type(4)));

// Async global->LDS, 16 B per lane. LDS dest must be WAVE-UNIFORM base;
// HW scatters lane i to base + i*16.
__device__ __forceinline__ void async_copy16(const void* g, void* l) {
  __builtin_amdgcn_global_load_lds(
      (const __attribute__((address_space(1))) void*)g,
      (__attribute__((address_space(3))) void*)l, 16, 0, 0);
}

// ---------------------------------------------------------------------------
// Fused prep: blocks [0,2048) x->bf16 cvt; [2048,2560) RoPE table;
// [2560,3584) weight transpose+cvt (4 mats x 256 tile-blocks).
// ---------------------------------------------------------------------------
__global__ __launch_bounds__(256) void prep_kernel(
    const float* __restrict__ x, const int* __restrict__ pos,
    const float* __restrict__ W0, const float* __restrict__ W1,
    const float* __restrict__ W2, const float* __restrict__ W3,
    __bf16* __restrict__ xb, float2* __restrict__ rtab,
    __bf16* __restrict__ T0, __bf16* __restrict__ T1,
    __bf16* __restrict__ T2, __bf16* __restrict__ T3) {
  __shared__ __bf16 tile[64][65];
  const int bid = blockIdx.x;
  const int t = threadIdx.x;
  if (bid < 2048) {
    const size_t i = ((size_t)bid * 256 + t) * 8;
    const float4 v0 = *(const float4*)(x + i);
    const float4 v1 = *(const float4*)(x + i + 4);
    bf16x8 o;
    o[0] = (__bf16)v0.x; o[1] = (__bf16)v0.y; o[2] = (__bf16)v0.z; o[3] = (__bf16)v0.w;
    o[4] = (__bf16)v1.x; o[5] = (__bf16)v1.y; o[6] = (__bf16)v1.z; o[7] = (__bf16)v1.w;
    *(bf16x8*)(xb + i) = o;
  } else if (bid < 2560) {
    const int idx = (bid - 2048) * 256 + t;  // 131072 = 4096*32
    const int m = idx >> 5, pi = idx & 31;
    const float inv = exp2f(-0.4152410118609203f * (float)pi);
    float sn, cs;
    __sincosf((float)pos[m] * inv, &sn, &cs);
    rtab[idx] = make_float2(cs, sn);
  } else {
    const int tid2 = bid - 2560;
    const int z = tid2 >> 8, rem = tid2 & 255;
    const float* W;
    __bf16* T;
    switch (z) {
      case 0: W = W0; T = T0; break;
      case 1: W = W1; T = T1; break;
      case 2: W = W2; T = T2; break;
      default: W = W3; T = T3; break;
    }
    const int k0 = (rem >> 4) * 64, n0 = (rem & 15) * 64;
    const int c = t & 63, rg = t >> 6;
#pragma unroll
    for (int i = 0; i < 16; i++) {
      const int r = rg + i * 4;
      tile[r][c] = (__bf16)W[(size_t)(k0 + r) * DD + n0 + c];
    }
    __syncthreads();
#pragma unroll
    for (int i = 0; i < 16; i++) {
      const int r = rg + i * 4;
      T[(size_t)(n0 + r) * DD + k0 + c] = tile[c][r];
    }
  }
}

// ---------------------------------------------------------------------------
// m97-style GEMM core with XOR chunk-swizzled LDS (conflict-free B-frag reads)
// C[128,128] += A[128,K] @ Bt[128,K]^T  (K = DD = 1024)
// ---------------------------------------------------------------------------
__device__ __forceinline__ void gemm_core(
    const __bf16* __restrict__ A, const __bf16* __restrict__ Bt,
    int bm, int bn, f32x4 (&acc)[4][4], __bf16* As, __bf16* Bs) {
  const int t = threadIdx.x;
  const int lane = t & 63, wave = t >> 6;
  const int col = lane & 15, quad = lane >> 4;
  const int wm = (wave & 1) * 64, wn = (wave >> 1) * 64;
  const int r8 = lane >> 3;             // row within 8-row slab
  const int cg = (lane & 7) ^ r8;       // swizzled global chunk
  const __bf16* ag = A + (size_t)(bm + wave * 32 + r8) * DD + cg * 8;
  const __bf16* bg = Bt + (size_t)(bn + wave * 32 + r8) * DD + cg * 8;
  __bf16* asb = As + wave * 32 * 64;
  __bf16* bsb = Bs + wave * 32 * 64;

  for (int kt = 0; kt < DD; kt += 64) {
#pragma unroll
    for (int c = 0; c < 4; c++) {
      async_copy16(ag + (size_t)c * 8 * DD + kt, asb + c * 512);
      async_copy16(bg + (size_t)c * 8 * DD + kt, bsb + c * 512);
    }
    __syncthreads();
#pragma unroll
    for (int ks = 0; ks < 2; ks++) {
      bf16x8 af[4], bf[4];
#pragma unroll
      for (int i = 0; i < 4; i++)
        af[i] = *(const bf16x8*)(As + (wm + i * 16 + col) * 64 +
                                 (((ks * 4 + quad) ^ (col & 7)) * 8));
#pragma unroll
      for (int j = 0; j < 4; j++)
        bf[j] = *(const bf16x8*)(Bs + (wn + j * 16 + col) * 64 +
                                 (((ks * 4 + quad) ^ (col & 7)) * 8));
#pragma unroll
      for (int i = 0; i < 4; i++)
#pragma unroll
        for (int j = 0; j < 4; j++)
          acc[i][j] =
              __builtin_amdgcn_mfma_f32_16x16x32_bf16(af[i], bf[j], acc[i][j], 0, 0, 0);
    }
    __syncthreads();
  }
}

// ---------------------------------------------------------------------------
// Fused Q/K/V projection. grid (24, 32): blockIdx.x = mat*8 + n-tile.
// Q,K: RoPE via table, scatter [B,H,S,DK].
// V: operand-swapped MFMA (C^T = Wv^T x^T) -> written DIRECTLY in [B,H,DK,S].
// ---------------------------------------------------------------------------
__global__ __launch_bounds__(256) void qkv_gemm_kernel(
    const __bf16* __restrict__ xb, const __bf16* __restrict__ WqT,
    const __bf16* __restrict__ WkT, const __bf16* __restrict__ WvT,
    const float* __restrict__ bq, const float* __restrict__ bk,
    const float* __restrict__ bv, const float2* __restrict__ ropetab,
    __bf16* __restrict__ qo, __bf16* __restrict__ ko, __bf16* __restrict__ vo) {
  __shared__ __bf16 As[128 * 64];
  __shared__ __bf16 Bs[128 * 64];
  const int mat = blockIdx.x >> 3;
  const int bn = (blockIdx.x & 7) * 128;
  const int bm = blockIdx.y * 128;

  f32x4 acc[4][4] = {};
  const int t = threadIdx.x, lane = t & 63, wave = t >> 6;
  const int col = lane & 15, quad = lane >> 4;
  const int wm = (wave & 1) * 64, wn = (wave >> 1) * 64;

  if (mat == 2) {
    // A-operand = WvT rows (n-dim), B-operand = xb rows (m-dim)
    gemm_core(WvT, xb, bn, bm, acc, As, Bs);
    // acc[i][j][r] = Vt[n = bn+wm+i*16+quad*4+r][m = bm+wn+j*16+col]
    const int b = bm >> 11;
#pragma unroll
    for (int i = 0; i < 4; i++) {
#pragma unroll
      for (int r = 0; r < 4; r++) {
        const int n = bn + wm + i * 16 + quad * 4 + r;
        const float bb = bv[n];
        const int h = n >> 6, dk = n & 63;
        __bf16* vrow = vo + ((size_t)(b * HH + h) * DKK + dk) * SS;
#pragma unroll
        for (int j = 0; j < 4; j++) {
          const int m = bm + wn + j * 16 + col;
          vrow[m & (SS - 1)] = (__bf16)(acc[i][j][r] + bb);
        }
      }
    }
    return;
  }

  const __bf16* Bt = mat == 0 ? WqT : WkT;
  const float* bias = mat == 0 ? bq : bk;
  __bf16* out = mat == 0 ? qo : ko;
  gemm_core(xb, Bt, bm, bn, acc, As, Bs);

#pragma unroll
  for (int i = 0; i < 4; i++) {
#pragma unroll
    for (int j = 0; j < 4; j++) {
      const int n = bn + wn + j * 16 + col;
      const float bb = bias[n];
      const int pi = (n & 63) >> 1;
#pragma unroll
      for (int r = 0; r < 4; r++) {
        const int m = bm + wm + i * 16 + quad * 4 + r;
        float v = acc[i][j][r] + bb;
        {
          const float other = __shfl_xor(v, 1, 64);
          const float2 cssn = ropetab[(size_t)m * 32 + pi];
          v = (n & 1) ? (other * cssn.y + v * cssn.x)
                      : (v * cssn.x - other * cssn.y);
        }
        const int h = n >> 6, dk = n & 63;
        const int b = m >> 11, s = m & (SS - 1);
        out[((size_t)(b * HH + h) * SS + s) * DKK + dk] = (__bf16)v;
      }
    }
  }
}

// ---------------------------------------------------------------------------
// O projection: out[M,N] fp32 = ob[M,K] @ WoT[N,K]^T + bo. grid (8, 32).
// ---------------------------------------------------------------------------
__global__ __launch_bounds__(256) void oproj_gemm_kernel(
    const __bf16* __restrict__ ob, const __bf16* __restrict__ WoT,
    const float* __restrict__ bo, float* __restrict__ out) {
  __shared__ __bf16 As[128 * 64];
  __shared__ __bf16 Bs[128 * 64];
  const int bn = blockIdx.x * 128;
  const int bm = blockIdx.y * 128;
  f32x4 acc[4][4] = {};
  gemm_core(ob, WoT, bm, bn, acc, As, Bs);

  const int t = threadIdx.x, lane = t & 63, wave = t >> 6;
  const int col = lane & 15, quad = lane >> 4;
  const int wm = (wave & 1) * 64, wn = (wave >> 1) * 64;
#pragma unroll
  for (int i = 0; i < 4; i++) {
#pragma unroll
    for (int j = 0; j < 4; j++) {
      const int n = bn + wn + j * 16 + col;
      const float bb = bo[n];
#pragma unroll
      for (int r = 0; r < 4; r++) {
        const int m = bm + wm + i * 16 + quad * 4 + r;
        out[(size_t)m * DD + n] = acc[i][j][r] + bb;
      }
    }
  }
}

// ---------------------------------------------------------------------------
// MFMA flash attention: R6-proven shell (paired load-balanced grid,
// single-buffered K/V) + fixed-max softmax.
// Block = (bh, pair p): Q-tile p then 31-p -> 33 iters per block, constant.
// 4 waves x 16 Q-rows. K-tile = 64 tokens.
// p = exp(s/8 - 16) = 2^(s*C1 - C2); exp(-16) cancels in O = sum(p v)/sum(p).
// l kept as per-lane partials, reduced once per phase end.
// q,k in [B,H,S,DK]; vt in [B,H,DK,S]; o out [B,S,H,DK] bf16.
// ---------------------------------------------------------------------------
__global__ __launch_bounds__(256) void flash_attn_mfma_kernel(
    const __bf16* __restrict__ q, const __bf16* __restrict__ k,
    const __bf16* __restrict__ vt, __bf16* __restrict__ o) {
  __shared__ __bf16 Ks[64 * 64];       // [j][dk], chunk-swizzled
  __shared__ __bf16 Vs[64 * 64];       // [d][j],  chunk-swizzled
  __shared__ __bf16 Ps[4][16 * 72];    // per-wave [row][j], stride 72

  const int bh = blockIdx.x;   // 0..31
  const int pr = blockIdx.y;   // 0..15
  const int t = threadIdx.x, lane = t & 63, wave = t >> 6;
  const int col = lane & 15, quad = lane >> 4;
  const int r8 = lane >> 3;            // row in 8-row slab
  const int cg = (lane & 7) ^ r8;      // swizzled global chunk

  const __bf16* qb = q + (size_t)bh * SS * DKK;
  const __bf16* kb = k + (size_t)bh * SS * DKK;
  const __bf16* vtb = vt + (size_t)bh * DKK * SS;
  const int b = bh / HH, h = bh % HH;
  __bf16* pw = (__bf16*)Ps[wave];

#pragma unroll
  for (int phase = 0; phase < 2; phase++) {
    const int qt = phase == 0 ? pr : (31 - pr);
    const int rbase = qt * 64 + wave * 16;

    // Q fragments for this phase (held in registers)
    bf16x8 qf[2];
#pragma unroll
    for (int ks = 0; ks < 2; ks++)
      qf[ks] = *(const bf16x8*)(qb + (size_t)(rbase + col) * DKK + ks * 32 +
                                quad * 8);

    f32x4 oacc[4] = {};
    float l_lane[4] = {0.f, 0.f, 0.f, 0.f};

    for (int kt = 0; kt <= qt; kt++) {
      // Stage K tile [64][64] and Vt tile [64][64]; wave w covers slabs
      // w*2 and w*2+1 (8 rows each).
#pragma unroll
      for (int i = 0; i < 2; i++) {
        const int slab = wave * 2 + i;
        async_copy16(kb + (size_t)(kt * 64 + slab * 8 + r8) * DKK + cg * 8,
                     Ks + slab * 512);
        async_copy16(vtb + (size_t)(slab * 8 + r8) * SS + kt * 64 + cg * 8,
                     Vs + slab * 512);
      }
      __syncthreads();

      // ---- QK^T: sc[ct], D-row = quad*4+r, D-col(token) = ct*16+col ----
      f32x4 sc[4] = {};
#pragma unroll
      for (int ct = 0; ct < 4; ct++)
#pragma unroll
        for (int ks = 0; ks < 2; ks++) {
          const bf16x8 kf = *(const bf16x8*)(Ks + (ct * 16 + col) * 64 +
                                             (((ks * 4 + quad) ^ (col & 7)) * 8));
          sc[ct] = __builtin_amdgcn_mfma_f32_16x16x32_bf16(qf[ks], kf, sc[ct],
                                                           0, 0, 0);
        }

      // ---- fixed-max softmax: p = 2^(s*C1 - C2); store P, accumulate l ----
      const bool diag = (kt == qt);
#pragma unroll
      for (int ct = 0; ct < 4; ct++)
#pragma unroll
        for (int r = 0; r < 4; r++) {
          float p = exp2f(sc[ct][r] * kC1 - kC2);
          if (diag && (kt * 64 + ct * 16 + col) > (rbase + quad * 4 + r))
            p = 0.0f;
          l_lane[r] += p;
          pw[(quad * 4 + r) * 72 + ct * 16 + col] = (__bf16)p;
        }

      // ---- PV: O[16 rows][dt*16+col] += P @ Vt^T (wave-private P) ----
      {
        bf16x8 pf[2];
#pragma unroll
        for (int ks = 0; ks < 2; ks++)
          pf[ks] = *(const bf16x8*)(pw + col * 72 + ks * 32 + quad * 8);
#pragma unroll
        for (int dt = 0; dt < 4; dt++)
#pragma unroll
          for (int ks = 0; ks < 2; ks++) {
            const bf16x8 vf = *(const bf16x8*)(Vs + (dt * 16 + col) * 64 +
                                               (((ks * 4 + quad) ^ (col & 7)) * 8));
            oacc[dt] = __builtin_amdgcn_mfma_f32_16x16x32_bf16(pf[ks], vf,
                                                               oacc[dt], 0, 0, 0);
          }
      }
      __syncthreads();
    }

    // Phase epilogue: reduce l over 16 token-lanes, normalize, write o
#pragma unroll
    for (int r = 0; r < 4; r++) {
      float l = l_lane[r];
#pragma unroll
      for (int w = 1; w < 16; w <<= 1) l += __shfl_xor(l, w, 64);
      const float inv_l = 1.0f / l;
      const int s = rbase + quad * 4 + r;
#pragma unroll
      for (int dt = 0; dt < 4; dt++)
        o[((size_t)(b * SS + s) * HH + h) * DKK + dt * 16 + col] =
            (__bf16)(oacc[dt][r] * inv_l);
    }
  }
}

// ---------------------------------------------------------------------------
extern "C" void kernel_launch(void* const* d_in, const int* in_sizes, int n_in,
                              void* d_out, int out_size, void* d_ws,
                              size_t ws_size, hipStream_t stream) {
  const float* x  = (const float*)d_in[0];
  const int*  pos = (const int*)d_in[1];
  const float* Wq = (const float*)d_in[2];
  const float* bq = (const float*)d_in[3];
  const float* Wk = (const float*)d_in[4];
  const float* bk = (const float*)d_in[5];
  const float* Wv = (const float*)d_in[6];
  const float* bv = (const float*)d_in[7];
  const float* Wo = (const float*)d_in[8];
  const float* bo = (const float*)d_in[9];
  float* out = (float*)d_out;

  char* ws = (char*)d_ws;
  __bf16* xb  = (__bf16*)(ws);                          // 8 MB
  __bf16* WqT = (__bf16*)(ws + ((size_t)8  << 20));     // 2 MB each
  __bf16* WkT = (__bf16*)(ws + ((size_t)10 << 20));
  __bf16* WvT = (__bf16*)(ws + ((size_t)12 << 20));
  __bf16* WoT = (__bf16*)(ws + ((size_t)14 << 20));
  __bf16* qb  = (__bf16*)(ws + ((size_t)16 << 20));     // 8 MB each
  __bf16* kb  = (__bf16*)(ws + ((size_t)24 << 20));
  __bf16* vtb = (__bf16*)(ws + ((size_t)32 << 20));     // V, transposed layout
  __bf16* ob  = (__bf16*)(ws + ((size_t)40 << 20));
  float2* rtab = (float2*)(ws + ((size_t)48 << 20));    // 1 MB; total 49 MB

  prep_kernel<<<3584, 256, 0, stream>>>(x, pos, Wq, Wk, Wv, Wo, xb, rtab, WqT,
                                        WkT, WvT, WoT);
  qkv_gemm_kernel<<<dim3(24, 32), 256, 0, stream>>>(xb, WqT, WkT, WvT, bq, bk,
                                                    bv, rtab, qb, kb, vtb);
  flash_attn_mfma_kernel<<<dim3(32, 16), 256, 0, stream>>>(qb, kb, vtb, ob);
  oproj_gemm_kernel<<<dim3(8, 32), 256, 0, stream>>>(ob, WoT, bo, out);
}